// Round 1
// baseline (285.700 us; speedup 1.0000x reference)
//
#include <hip/hip_runtime.h>

#define NN 100000
#define DEG 16
#define NF 128
#define HID 128
#define NC 16
#define NB 10000

// ---------------------------------------------------------------------------
// GEMM1: Q[n][j] = sum_k X[n][k]*W1[j][k]   (blockIdx.y==0)
//        P[n][j] = sum_k X[n][k]*W1[j][128+k] (blockIdx.y==1)
// Tile: 128 rows x 128 cols, K=128 fully LDS-resident. 256 thr, 8x8/thread.
// ---------------------------------------------------------------------------
__global__ __launch_bounds__(256)
void gemm_qp(const float* __restrict__ X, const float* __restrict__ W1,
             float* __restrict__ Q, float* __restrict__ P) {
    extern __shared__ float sm[];
    float* sA = sm;              // [128][132]
    float* sB = sm + 128 * 132;  // [128][132]  sB[k][j] = W1[j][ct*128+k]
    const int t = threadIdx.x;
    const int row0 = blockIdx.x * 128;
    const int ct = blockIdx.y;

    // stage A tile (coalesced float4)
    {
        const int c4 = (t & 31) * 4;
        const int rg = t >> 5;
        #pragma unroll
        for (int i = 0; i < 16; ++i) {
            const int r = rg + 8 * i;
            int grow = row0 + r;
            if (grow > NN - 1) grow = NN - 1;  // clamp: stores are guarded
            const float4 v = *(const float4*)(X + (size_t)grow * NF + c4);
            *(float4*)(sA + r * 132 + c4) = v;
        }
    }
    // stage B tile (transpose W1 slice into [k][j])
    {
        const int j = t & 127;
        const int k0 = (t >> 7) * 64;
        const float* wrow = W1 + (size_t)j * 256 + ct * 128 + k0;
        #pragma unroll
        for (int q = 0; q < 16; ++q) {
            const float4 v = *(const float4*)(wrow + q * 4);
            sB[(k0 + q * 4 + 0) * 132 + j] = v.x;
            sB[(k0 + q * 4 + 1) * 132 + j] = v.y;
            sB[(k0 + q * 4 + 2) * 132 + j] = v.z;
            sB[(k0 + q * 4 + 3) * 132 + j] = v.w;
        }
    }
    __syncthreads();

    const int tr = t >> 4;       // 0..15 (rows tr + 16*i -> distinct banks)
    const int tc = t & 15;       // 0..15
    const int c0 = tc * 4;
    const int c1 = 64 + tc * 4;
    float4 acc0[8], acc1[8];
    #pragma unroll
    for (int i = 0; i < 8; ++i) { acc0[i] = float4{0,0,0,0}; acc1[i] = float4{0,0,0,0}; }

    for (int k = 0; k < 128; k += 4) {
        float4 av[8];
        #pragma unroll
        for (int i = 0; i < 8; ++i)
            av[i] = *(const float4*)(sA + (tr + 16 * i) * 132 + k);
        #pragma unroll
        for (int q = 0; q < 4; ++q) {
            const float4 b0 = *(const float4*)(sB + (k + q) * 132 + c0);
            const float4 b1 = *(const float4*)(sB + (k + q) * 132 + c1);
            #pragma unroll
            for (int i = 0; i < 8; ++i) {
                const float a = (q == 0) ? av[i].x : (q == 1) ? av[i].y
                               : (q == 2) ? av[i].z : av[i].w;
                acc0[i].x += a * b0.x; acc0[i].y += a * b0.y;
                acc0[i].z += a * b0.z; acc0[i].w += a * b0.w;
                acc1[i].x += a * b1.x; acc1[i].y += a * b1.y;
                acc1[i].z += a * b1.z; acc1[i].w += a * b1.w;
            }
        }
    }

    float* OUT = ct ? P : Q;
    #pragma unroll
    for (int i = 0; i < 8; ++i) {
        const int grow = row0 + tr + 16 * i;
        if (grow < NN) {
            *(float4*)(OUT + (size_t)grow * HID + c0) = acc0[i];
            *(float4*)(OUT + (size_t)grow * HID + c1) = acc1[i];
        }
    }
}

// ---------------------------------------------------------------------------
// Aggregate: h1[n][c] = relu(Q[n][c] + (1/16) * sum_d P[nbr(n,d)][c])
// In-place over Q. 32 lanes (float4 each) cover one node's 128 cols.
// ---------------------------------------------------------------------------
__global__ __launch_bounds__(256)
void aggregate(const int* __restrict__ nidx, const float* __restrict__ P,
               float* __restrict__ QH) {
    const int g = blockIdx.x * 256 + threadIdx.x;
    const int node = g >> 5;
    const int c4 = (g & 31) * 4;
    const int* nb = nidx + (size_t)node * DEG;
    float4 s{0, 0, 0, 0};
    #pragma unroll
    for (int d = 0; d < DEG; ++d) {
        const float4 v = *(const float4*)(P + (size_t)nb[d] * HID + c4);
        s.x += v.x; s.y += v.y; s.z += v.z; s.w += v.w;
    }
    float4 q = *(const float4*)(QH + (size_t)node * HID + c4);
    const float inv = 1.0f / 16.0f;
    q.x = fmaxf(fmaf(s.x, inv, q.x), 0.f);
    q.y = fmaxf(fmaf(s.y, inv, q.y), 0.f);
    q.z = fmaxf(fmaf(s.z, inv, q.z), 0.f);
    q.w = fmaxf(fmaf(s.w, inv, q.w), 0.f);
    *(float4*)(QH + (size_t)node * HID + c4) = q;
}

// ---------------------------------------------------------------------------
// GEMM2: ST[n][j2] with j2<16 -> S (W2[:,:128]), j2>=16 -> T (W2[:,128:])
// Tile 128 rows x 32 cols, K=128 LDS-resident, 256 thr, 4 rows x 1 float4 each.
// ---------------------------------------------------------------------------
__global__ __launch_bounds__(256)
void gemm_st(const float* __restrict__ H, const float* __restrict__ W2,
             float* __restrict__ ST) {
    extern __shared__ float sm[];
    float* sA = sm;              // [128][132]
    float* sB = sm + 128 * 132;  // [128][36]  sB[k][j2] = W2[j2&15][(j2>>4)*128+k]
    const int t = threadIdx.x;
    const int row0 = blockIdx.x * 128;

    {
        const int c4 = (t & 31) * 4;
        const int rg = t >> 5;
        #pragma unroll
        for (int i = 0; i < 16; ++i) {
            const int r = rg + 8 * i;
            int grow = row0 + r;
            if (grow > NN - 1) grow = NN - 1;
            const float4 v = *(const float4*)(H + (size_t)grow * HID + c4);
            *(float4*)(sA + r * 132 + c4) = v;
        }
    }
    {
        const int j2 = t & 31;
        const int k0 = (t >> 5) * 16;
        const float* wrow = W2 + (size_t)(j2 & 15) * 256 + (j2 >> 4) * 128 + k0;
        #pragma unroll
        for (int q = 0; q < 4; ++q) {
            const float4 v = *(const float4*)(wrow + q * 4);
            sB[(k0 + q * 4 + 0) * 36 + j2] = v.x;
            sB[(k0 + q * 4 + 1) * 36 + j2] = v.y;
            sB[(k0 + q * 4 + 2) * 36 + j2] = v.z;
            sB[(k0 + q * 4 + 3) * 36 + j2] = v.w;
        }
    }
    __syncthreads();

    const int tr = t >> 3;   // 0..31, rows tr + 32*i
    const int tc = t & 7;    // 0..7
    const int c0 = tc * 4;
    float4 acc[4];
    #pragma unroll
    for (int i = 0; i < 4; ++i) acc[i] = float4{0, 0, 0, 0};

    for (int k = 0; k < 128; k += 4) {
        float4 av[4];
        #pragma unroll
        for (int i = 0; i < 4; ++i)
            av[i] = *(const float4*)(sA + (tr + 32 * i) * 132 + k);
        #pragma unroll
        for (int q = 0; q < 4; ++q) {
            const float4 b = *(const float4*)(sB + (k + q) * 36 + c0);
            #pragma unroll
            for (int i = 0; i < 4; ++i) {
                const float a = (q == 0) ? av[i].x : (q == 1) ? av[i].y
                               : (q == 2) ? av[i].z : av[i].w;
                acc[i].x += a * b.x; acc[i].y += a * b.y;
                acc[i].z += a * b.z; acc[i].w += a * b.w;
            }
        }
    }
    #pragma unroll
    for (int i = 0; i < 4; ++i) {
        const int grow = row0 + tr + 32 * i;
        if (grow < NN)
            *(float4*)(ST + (size_t)grow * 32 + c0) = acc[i];
    }
}

// ---------------------------------------------------------------------------
// Final: out[b][j] = S[node_b][j] + (1/16)*sum_d T[nbr(node_b,d)][j]
// ---------------------------------------------------------------------------
__global__ __launch_bounds__(256)
void final_out(const int* __restrict__ nodes, const int* __restrict__ nidx,
               const float* __restrict__ ST, float* __restrict__ out) {
    const int g = blockIdx.x * 256 + threadIdx.x;
    const int b = g >> 4;
    const int j = g & 15;
    const int node = nodes[b];
    const float s = ST[(size_t)node * 32 + j];
    const int* nb = nidx + (size_t)node * DEG;
    float acc = 0.f;
    #pragma unroll
    for (int d = 0; d < DEG; ++d)
        acc += ST[(size_t)nb[d] * 32 + 16 + j];
    out[g] = fmaf(acc, 1.0f / 16.0f, s);
}

extern "C" void kernel_launch(void* const* d_in, const int* in_sizes, int n_in,
                              void* d_out, int out_size, void* d_ws, size_t ws_size,
                              hipStream_t stream) {
    const int* nodes = (const int*)d_in[0];
    const int* nidx  = (const int*)d_in[1];
    const float* X   = (const float*)d_in[2];
    const float* W1  = (const float*)d_in[3];
    const float* W2  = (const float*)d_in[4];
    float* out = (float*)d_out;

    // ws layout: Q (-> h1 in place) | P | ST   = 115.2 MB total
    float* Q  = (float*)d_ws;
    float* P  = Q + (size_t)NN * HID;
    float* ST = P + (size_t)NN * HID;

    const size_t sm1 = (size_t)(128 * 132 + 128 * 132) * sizeof(float);
    gemm_qp<<<dim3(782, 2), 256, sm1, stream>>>(X, W1, Q, P);

    aggregate<<<(NN * 32) / 256, 256, 0, stream>>>(nidx, P, Q);

    const size_t sm2 = (size_t)(128 * 132 + 128 * 36) * sizeof(float);
    gemm_st<<<782, 256, sm2, stream>>>(Q, W2, ST);

    final_out<<<(NB * NC) / 256, 256, 0, stream>>>(nodes, nidx, ST, out);
}

// Round 2
// 173.780 us; speedup vs baseline: 1.6440x; 1.6440x over previous
//
#include <hip/hip_runtime.h>
#include <hip/hip_bf16.h>

#define NN 100000
#define DEG 16
#define NF 128
#define HID 128
#define NC 16
#define NB 10000

typedef float f32x16 __attribute__((ext_vector_type(16)));
typedef short s16x8 __attribute__((ext_vector_type(8)));

__device__ __forceinline__ ushort f2bf(float f) {
    unsigned u = __builtin_bit_cast(unsigned, f);
    return (ushort)((u + 0x7FFFu + ((u >> 16) & 1u)) >> 16);
}
__device__ __forceinline__ float bf2f(ushort h) {
    return __builtin_bit_cast(float, (unsigned)h << 16);
}
// swizzled byte address in a [128][128]-bf16 LDS tile (256B rows, T2 pattern)
__device__ __forceinline__ int swz(int row, int byteoff) {
    return row * 256 + (byteoff ^ ((row & 7) << 4));
}

// ---------------------------------------------------------------------------
// GEMM1 (split-bf16 MFMA): out[n][col'] = sum_k X[n][k] * Wb[col'][k]
//   block col-half ct=0 -> Q (fp32), ct=1 -> P (bf16)
//   Wb[c][k] = W1[c][ct*128 + k]  (row-major fp32 source, converted in-kernel)
//   X = Xh + Xl, W = Wh + Wl; acc = Xh*Wh + Xl*Wh + Xh*Wl  (3 MFMA passes)
// ---------------------------------------------------------------------------
__global__ __launch_bounds__(256)
void gemm1_mfma(const float* __restrict__ X, const float* __restrict__ W1,
                float* __restrict__ Q, ushort* __restrict__ Pb) {
    extern __shared__ char lds[];
    char* Ah = lds;
    char* Al = lds + 32768;
    char* Bh = lds + 65536;
    char* Bl = lds + 98304;

    // bijective XCD swizzle (nwg=1564, m204): pairs (2k,2k+1) share an XCD L2
    const int orig = blockIdx.x;
    const int qq = 1564 / 8, rr = 1564 % 8;
    const int xcd = orig & 7;
    const int pos = orig >> 3;
    const int wgid = (xcd < rr ? xcd * (qq + 1) : rr * (qq + 1) + (xcd - rr) * qq) + pos;
    const int bx = wgid >> 1;
    const int ct = wgid & 1;
    const int row0 = bx * 128;

    const int t = threadIdx.x;
    const int srow = t >> 1;           // 0..127
    const int scol = (t & 1) * 64;     // element offset within row

    // ---- stage X tile -> Ah/Al (convert fp32 -> bf16 hi/lo, swizzled writes)
    {
        int grow = row0 + srow; if (grow > NN - 1) grow = NN - 1;
        const float* src = X + (size_t)grow * NF + scol;
        #pragma unroll
        for (int i = 0; i < 8; ++i) {
            float4 a = *(const float4*)(src + i * 8);
            float4 b = *(const float4*)(src + i * 8 + 4);
            float v[8] = {a.x, a.y, a.z, a.w, b.x, b.y, b.z, b.w};
            ushort hh[8], ll[8];
            #pragma unroll
            for (int j = 0; j < 8; ++j) {
                hh[j] = f2bf(v[j]);
                ll[j] = f2bf(v[j] - bf2f(hh[j]));
            }
            const int bo = scol * 2 + i * 16;
            *(uint4*)(Ah + swz(srow, bo)) = *(const uint4*)hh;
            *(uint4*)(Al + swz(srow, bo)) = *(const uint4*)ll;
        }
    }
    // ---- stage W tile -> Bh/Bl   (Wb[c][k] = W1[c][ct*128+k])
    {
        const float* src = W1 + (size_t)srow * 256 + ct * 128 + scol;
        #pragma unroll
        for (int i = 0; i < 8; ++i) {
            float4 a = *(const float4*)(src + i * 8);
            float4 b = *(const float4*)(src + i * 8 + 4);
            float v[8] = {a.x, a.y, a.z, a.w, b.x, b.y, b.z, b.w};
            ushort hh[8], ll[8];
            #pragma unroll
            for (int j = 0; j < 8; ++j) {
                hh[j] = f2bf(v[j]);
                ll[j] = f2bf(v[j] - bf2f(hh[j]));
            }
            const int bo = scol * 2 + i * 16;
            *(uint4*)(Bh + swz(srow, bo)) = *(const uint4*)hh;
            *(uint4*)(Bl + swz(srow, bo)) = *(const uint4*)ll;
        }
    }
    __syncthreads();

    // ---- compute: 4 waves, each a 64x64 tile (2x2 frags of 32x32)
    const int lane = t & 63;
    const int w = t >> 6;
    const int wm = w >> 1, wn = w & 1;
    const int lr = lane & 31;
    const int lkb = (lane >> 5) * 16;  // k byte offset (8 bf16)

    f32x16 acc00 = {0,0,0,0,0,0,0,0,0,0,0,0,0,0,0,0};
    f32x16 acc01 = acc00, acc10 = acc00, acc11 = acc00;

    #pragma unroll
    for (int pass = 0; pass < 3; ++pass) {
        const char* Ab = (pass == 1) ? Al : Ah;
        const char* Bb = (pass == 2) ? Bl : Bh;
        #pragma unroll
        for (int kk = 0; kk < 8; ++kk) {
            const int kb = kk * 32 + lkb;
            s16x8 a0 = *(const s16x8*)(Ab + swz(wm * 64 + lr, kb));
            s16x8 a1 = *(const s16x8*)(Ab + swz(wm * 64 + 32 + lr, kb));
            s16x8 b0 = *(const s16x8*)(Bb + swz(wn * 64 + lr, kb));
            s16x8 b1 = *(const s16x8*)(Bb + swz(wn * 64 + 32 + lr, kb));
            acc00 = __builtin_amdgcn_mfma_f32_32x32x16_bf16(a0, b0, acc00, 0, 0, 0);
            acc01 = __builtin_amdgcn_mfma_f32_32x32x16_bf16(a0, b1, acc01, 0, 0, 0);
            acc10 = __builtin_amdgcn_mfma_f32_32x32x16_bf16(a1, b0, acc10, 0, 0, 0);
            acc11 = __builtin_amdgcn_mfma_f32_32x32x16_bf16(a1, b1, acc11, 0, 0, 0);
        }
    }

    // ---- epilogue: C/D layout col=lane&31, row=(g&3)+8*(g>>2)+4*(lane>>5)
    const int ccol = lane & 31;
    const int crow4 = 4 * (lane >> 5);
    #pragma unroll
    for (int m = 0; m < 2; ++m) {
        #pragma unroll
        for (int n = 0; n < 2; ++n) {
            const f32x16 acc = (m == 0) ? ((n == 0) ? acc00 : acc01)
                                        : ((n == 0) ? acc10 : acc11);
            const int col = wn * 64 + n * 32 + ccol;
            #pragma unroll
            for (int g = 0; g < 16; ++g) {
                const int row = wm * 64 + m * 32 + (g & 3) + 8 * (g >> 2) + crow4;
                const int grow = row0 + row;
                if (grow < NN) {
                    if (ct == 0) Q[(size_t)grow * HID + col] = acc[g];
                    else         Pb[(size_t)grow * HID + col] = f2bf(acc[g]);
                }
            }
        }
    }
}

// ---------------------------------------------------------------------------
// Aggregate: h1[n][c] = relu(Q[n][c] + (1/16) * sum_d Pb[nbr(n,d)][c])
// 16 lanes per node; ushort8 (16B) row slices; neighbor ids via shfl.
// ---------------------------------------------------------------------------
__global__ __launch_bounds__(256)
void aggregate(const int* __restrict__ nidx, const ushort* __restrict__ Pb,
               float* __restrict__ QH) {
    const int g = blockIdx.x * 256 + threadIdx.x;
    const int node = g >> 4;
    const int lane = g & 15;
    const int myn = nidx[(size_t)node * DEG + lane];
    float s[8] = {0, 0, 0, 0, 0, 0, 0, 0};
    #pragma unroll
    for (int d = 0; d < DEG; ++d) {
        const int id = __shfl(myn, d, 16);
        s16x8 v = *(const s16x8*)(Pb + (size_t)id * HID + lane * 8);
        #pragma unroll
        for (int j = 0; j < 8; ++j) s[j] += bf2f((ushort)v[j]);
    }
    float* dst = QH + (size_t)node * HID + lane * 8;
    float4 q0 = *(const float4*)(dst);
    float4 q1 = *(const float4*)(dst + 4);
    const float inv = 1.0f / 16.0f;
    q0.x = fmaxf(fmaf(s[0], inv, q0.x), 0.f);
    q0.y = fmaxf(fmaf(s[1], inv, q0.y), 0.f);
    q0.z = fmaxf(fmaf(s[2], inv, q0.z), 0.f);
    q0.w = fmaxf(fmaf(s[3], inv, q0.w), 0.f);
    q1.x = fmaxf(fmaf(s[4], inv, q1.x), 0.f);
    q1.y = fmaxf(fmaf(s[5], inv, q1.y), 0.f);
    q1.z = fmaxf(fmaf(s[6], inv, q1.z), 0.f);
    q1.w = fmaxf(fmaf(s[7], inv, q1.w), 0.f);
    *(float4*)dst = q0;
    *(float4*)(dst + 4) = q1;
}

// ---------------------------------------------------------------------------
// GEMM2 (fp32): ST[n][j2], j2<16 -> S (W2[:,:128]), j2>=16 -> T (W2[:,128:])
// ---------------------------------------------------------------------------
__global__ __launch_bounds__(256)
void gemm_st(const float* __restrict__ H, const float* __restrict__ W2,
             float* __restrict__ ST) {
    extern __shared__ float sm[];
    float* sA = sm;              // [128][132]
    float* sB = sm + 128 * 132;  // [128][36]
    const int t = threadIdx.x;
    const int row0 = blockIdx.x * 128;

    {
        const int c4 = (t & 31) * 4;
        const int rg = t >> 5;
        #pragma unroll
        for (int i = 0; i < 16; ++i) {
            const int r = rg + 8 * i;
            int grow = row0 + r;
            if (grow > NN - 1) grow = NN - 1;
            const float4 v = *(const float4*)(H + (size_t)grow * HID + c4);
            *(float4*)(sA + r * 132 + c4) = v;
        }
    }
    {
        const int j2 = t & 31;
        const int k0 = (t >> 5) * 16;
        const float* wrow = W2 + (size_t)(j2 & 15) * 256 + (j2 >> 4) * 128 + k0;
        #pragma unroll
        for (int q = 0; q < 4; ++q) {
            const float4 v = *(const float4*)(wrow + q * 4);
            sB[(k0 + q * 4 + 0) * 36 + j2] = v.x;
            sB[(k0 + q * 4 + 1) * 36 + j2] = v.y;
            sB[(k0 + q * 4 + 2) * 36 + j2] = v.z;
            sB[(k0 + q * 4 + 3) * 36 + j2] = v.w;
        }
    }
    __syncthreads();

    const int tr = t >> 3;
    const int tc = t & 7;
    const int c0 = tc * 4;
    float4 acc[4];
    #pragma unroll
    for (int i = 0; i < 4; ++i) acc[i] = float4{0, 0, 0, 0};

    for (int k = 0; k < 128; k += 4) {
        float4 av[4];
        #pragma unroll
        for (int i = 0; i < 4; ++i)
            av[i] = *(const float4*)(sA + (tr + 32 * i) * 132 + k);
        #pragma unroll
        for (int q = 0; q < 4; ++q) {
            const float4 b = *(const float4*)(sB + (k + q) * 36 + c0);
            #pragma unroll
            for (int i = 0; i < 4; ++i) {
                const float a = (q == 0) ? av[i].x : (q == 1) ? av[i].y
                               : (q == 2) ? av[i].z : av[i].w;
                acc[i].x += a * b.x; acc[i].y += a * b.y;
                acc[i].z += a * b.z; acc[i].w += a * b.w;
            }
        }
    }
    #pragma unroll
    for (int i = 0; i < 4; ++i) {
        const int grow = row0 + tr + 32 * i;
        if (grow < NN)
            *(float4*)(ST + (size_t)grow * 32 + c0) = acc[i];
    }
}

// ---------------------------------------------------------------------------
// Final: out[b][j] = S[node_b][j] + (1/16)*sum_d T[nbr(node_b,d)][j]
// ---------------------------------------------------------------------------
__global__ __launch_bounds__(256)
void final_out(const int* __restrict__ nodes, const int* __restrict__ nidx,
               const float* __restrict__ ST, float* __restrict__ out) {
    const int g = blockIdx.x * 256 + threadIdx.x;
    const int b = g >> 4;
    const int j = g & 15;
    const int node = nodes[b];
    const float s = ST[(size_t)node * 32 + j];
    const int* nb = nidx + (size_t)node * DEG;
    float acc = 0.f;
    #pragma unroll
    for (int d = 0; d < DEG; ++d)
        acc += ST[(size_t)nb[d] * 32 + 16 + j];
    out[g] = fmaf(acc, 1.0f / 16.0f, s);
}

extern "C" void kernel_launch(void* const* d_in, const int* in_sizes, int n_in,
                              void* d_out, int out_size, void* d_ws, size_t ws_size,
                              hipStream_t stream) {
    const int* nodes = (const int*)d_in[0];
    const int* nidx  = (const int*)d_in[1];
    const float* X   = (const float*)d_in[2];
    const float* W1  = (const float*)d_in[3];
    const float* W2  = (const float*)d_in[4];
    float* out = (float*)d_out;

    // ws: Q/h1 fp32 (51.2MB) | Pb bf16 (25.6MB) | ST fp32 (12.8MB)
    float* Q   = (float*)d_ws;
    ushort* Pb = (ushort*)((char*)d_ws + (size_t)NN * HID * 4);
    float* ST  = (float*)((char*)d_ws + (size_t)NN * HID * 4 + (size_t)NN * HID * 2);

    gemm1_mfma<<<1564, 256, 131072, stream>>>(X, W1, Q, Pb);
    aggregate<<<(NN * 16) / 256, 256, 0, stream>>>(nidx, Pb, Q);
    const size_t sm2 = (size_t)(128 * 132 + 128 * 36) * sizeof(float);
    gemm_st<<<782, 256, sm2, stream>>>(Q, W2, ST);
    final_out<<<(NB * NC) / 256, 256, 0, stream>>>(nodes, nidx, ST, out);
}

// Round 3
// 120.226 us; speedup vs baseline: 2.3764x; 1.4455x over previous
//
#include <hip/hip_runtime.h>
#include <hip/hip_bf16.h>

#define NN 100000
#define DEG 16
#define NF 128
#define HID 128
#define NC 16
#define NB 10000

typedef float f32x16 __attribute__((ext_vector_type(16)));
typedef short s16x8 __attribute__((ext_vector_type(8)));

__device__ __forceinline__ ushort f2bf(float f) {   // round-to-nearest-even
    unsigned u = __builtin_bit_cast(unsigned, f);
    return (ushort)((u + 0x7FFFu + ((u >> 16) & 1u)) >> 16);
}
__device__ __forceinline__ float bf2f(ushort h) {
    return __builtin_bit_cast(float, (unsigned)h << 16);
}

// split one fp32 into bf16 hi (truncate) + bf16 lo (residual, truncate)
__device__ __forceinline__ void cvt_hilo8(float4 a, float4 b, s16x8* h, s16x8* l) {
    float v[8] = {a.x, a.y, a.z, a.w, b.x, b.y, b.z, b.w};
    ushort hh[8], ll[8];
    #pragma unroll
    for (int j = 0; j < 8; ++j) {
        const unsigned u = __builtin_bit_cast(unsigned, v[j]);
        hh[j] = (ushort)(u >> 16);
        const float hf = __builtin_bit_cast(float, u & 0xFFFF0000u);
        ll[j] = (ushort)(__builtin_bit_cast(unsigned, v[j] - hf) >> 16);
    }
    *h = *(s16x8*)hh;
    *l = *(s16x8*)ll;
}

// ---------------------------------------------------------------------------
// Prep: lay W1 (hi/lo) and W2 (single bf16) out in MFMA B-fragment order.
// WF1: frag (c,kk): lane l holds Wb[c*32+(l&31)][kk*16+(l>>5)*8 .. +8]
//   where Wb[j][k] = j<128 ? W1[j][k] : W1[j-128][128+k]
// WF2: frag (kk): lane l holds W2b[(l&31)][kk*16+(l>>5)*8 .. +8]
//   where W2b[j][k] = j<16 ? W2[j][k] : W2[j-16][128+k]
// 72 frags x 64 lanes = 4608 threads.
// ---------------------------------------------------------------------------
__global__ __launch_bounds__(256)
void wf_prep(const float* __restrict__ W1, const float* __restrict__ W2,
             ushort* __restrict__ WFh, ushort* __restrict__ WFl,
             ushort* __restrict__ WF2) {
    const int t = blockIdx.x * 256 + threadIdx.x;
    if (t >= 72 * 64) return;
    const int frag = t >> 6;
    const int lane = t & 63;
    const int k0 = (frag & 7) * 16 + (lane >> 5) * 8;

    if (frag < 64) {
        const int vcol = (frag >> 3) * 32 + (lane & 31);
        const float* src = (vcol < 128) ? W1 + (size_t)vcol * 256
                                        : W1 + (size_t)(vcol - 128) * 256 + 128;
        ushort hh[8], ll[8];
        #pragma unroll
        for (int j = 0; j < 8; ++j) {
            const float v = src[k0 + j];
            const unsigned u = __builtin_bit_cast(unsigned, v);
            hh[j] = (ushort)(u >> 16);
            const float hf = __builtin_bit_cast(float, u & 0xFFFF0000u);
            ll[j] = (ushort)(__builtin_bit_cast(unsigned, v - hf) >> 16);
        }
        *(uint4*)(WFh + (size_t)t * 8) = *(const uint4*)hh;
        *(uint4*)(WFl + (size_t)t * 8) = *(const uint4*)ll;
    } else {
        const int vcol = lane & 31;
        const float* src = (vcol < 16) ? W2 + (size_t)vcol * 256
                                       : W2 + (size_t)(vcol - 16) * 256 + 128;
        ushort hh[8];
        #pragma unroll
        for (int j = 0; j < 8; ++j) hh[j] = f2bf(src[k0 + j]);
        *(uint4*)(WF2 + (size_t)((frag - 64) * 64 + lane) * 8) = *(const uint4*)hh;
    }
}

// ---------------------------------------------------------------------------
// GEMM1 (no LDS): block = 128 rows x 256 cols, K=128.
// 4 waves: wm = row half (64 rows as 2x32 frags), wn = col half (128 cols as
// 4x32 frags). A from global fp32 (split hi/lo in regs), B from WFh/WFl.
// 3 MFMA products: Ah*Bh + Al*Bh + Ah*Bl. Out: cols<128 -> Qb, else Pb (bf16).
// ---------------------------------------------------------------------------
__global__ __launch_bounds__(256, 2)
void gemm1(const float* __restrict__ X,
           const ushort* __restrict__ WFh, const ushort* __restrict__ WFl,
           ushort* __restrict__ Qb, ushort* __restrict__ Pb) {
    const int t = threadIdx.x;
    const int lane = t & 63;
    const int w = t >> 6;
    const int wm = w >> 1, wn = w & 1;
    const int row0 = blockIdx.x * 128;

    int r0 = row0 + wm * 64 + (lane & 31);
    int r1 = r0 + 32;
    if (r0 > NN - 1) r0 = NN - 1;
    if (r1 > NN - 1) r1 = NN - 1;
    const float* a0p = X + (size_t)r0 * NF + (lane >> 5) * 8;
    const float* a1p = X + (size_t)r1 * NF + (lane >> 5) * 8;

    f32x16 acc[2][4];
    #pragma unroll
    for (int m = 0; m < 2; ++m)
        #pragma unroll
        for (int n = 0; n < 4; ++n)
            acc[m][n] = (f32x16){0,0,0,0,0,0,0,0,0,0,0,0,0,0,0,0};

    #pragma unroll
    for (int kk = 0; kk < 8; ++kk) {
        const float4 a0a = *(const float4*)(a0p + kk * 16);
        const float4 a0b = *(const float4*)(a0p + kk * 16 + 4);
        const float4 a1a = *(const float4*)(a1p + kk * 16);
        const float4 a1b = *(const float4*)(a1p + kk * 16 + 4);
        s16x8 a0h, a0l, a1h, a1l;
        cvt_hilo8(a0a, a0b, &a0h, &a0l);
        cvt_hilo8(a1a, a1b, &a1h, &a1l);
        #pragma unroll
        for (int n = 0; n < 4; ++n) {
            const size_t fo = (size_t)(((wn * 4 + n) * 8 + kk) * 64 + lane) * 8;
            const s16x8 bh = *(const s16x8*)(WFh + fo);
            const s16x8 bl = *(const s16x8*)(WFl + fo);
            acc[0][n] = __builtin_amdgcn_mfma_f32_32x32x16_bf16(a0h, bh, acc[0][n], 0, 0, 0);
            acc[1][n] = __builtin_amdgcn_mfma_f32_32x32x16_bf16(a1h, bh, acc[1][n], 0, 0, 0);
            acc[0][n] = __builtin_amdgcn_mfma_f32_32x32x16_bf16(a0l, bh, acc[0][n], 0, 0, 0);
            acc[1][n] = __builtin_amdgcn_mfma_f32_32x32x16_bf16(a1l, bh, acc[1][n], 0, 0, 0);
            acc[0][n] = __builtin_amdgcn_mfma_f32_32x32x16_bf16(a0h, bl, acc[0][n], 0, 0, 0);
            acc[1][n] = __builtin_amdgcn_mfma_f32_32x32x16_bf16(a1h, bl, acc[1][n], 0, 0, 0);
        }
    }

    // epilogue: C/D layout col=lane&31, row=(g&3)+8*(g>>2)+4*(lane>>5)
    const int ccol = lane & 31;
    const int crow4 = 4 * (lane >> 5);
    #pragma unroll
    for (int m = 0; m < 2; ++m) {
        #pragma unroll
        for (int n = 0; n < 4; ++n) {
            const int col = wn * 128 + n * 32 + ccol;
            ushort* base = (col < 128) ? (Qb + col) : (Pb + col - 128);
            #pragma unroll
            for (int g = 0; g < 16; ++g) {
                const int row = row0 + wm * 64 + m * 32 + (g & 3) + 8 * (g >> 2) + crow4;
                if (row < NN) base[(size_t)row * HID] = f2bf(acc[m][n][g]);
            }
        }
    }
}

// ---------------------------------------------------------------------------
// Aggregate: h1[n][c] = relu(Qb[n][c] + (1/16)*sum_d Pb[nbr(n,d)][c]), bf16 io
// 16 lanes per node; s16x8 (16B) row slices; neighbor ids via shfl.
// ---------------------------------------------------------------------------
__global__ __launch_bounds__(256)
void aggregate(const int* __restrict__ nidx, const ushort* __restrict__ Pb,
               ushort* __restrict__ Qb) {
    const int g = blockIdx.x * 256 + threadIdx.x;
    const int node = g >> 4;
    const int lane = g & 15;
    const int myn = nidx[(size_t)node * DEG + lane];
    float s[8] = {0, 0, 0, 0, 0, 0, 0, 0};
    #pragma unroll
    for (int d = 0; d < DEG; ++d) {
        const int id = __shfl(myn, d, 16);
        const s16x8 v = *(const s16x8*)(Pb + (size_t)id * HID + lane * 8);
        #pragma unroll
        for (int j = 0; j < 8; ++j) s[j] += bf2f((ushort)v[j]);
    }
    ushort* dst = Qb + (size_t)node * HID + lane * 8;
    const s16x8 q = *(const s16x8*)dst;
    ushort out[8];
    const float inv = 1.0f / 16.0f;
    #pragma unroll
    for (int j = 0; j < 8; ++j)
        out[j] = f2bf(fmaxf(fmaf(s[j], inv, bf2f((ushort)q[j])), 0.f));
    *(uint4*)dst = *(const uint4*)out;
}

// ---------------------------------------------------------------------------
// GEMM2 (bf16 MFMA, no LDS): block = 256 rows x 32 cols, K=128.
// Wave w: rows block*256 + w*64 (2x32 frags). Single bf16 pass.
// ST[n][j2]: j2<16 -> S, j2>=16 -> T.
// ---------------------------------------------------------------------------
__global__ __launch_bounds__(256, 2)
void gemm2(const ushort* __restrict__ Hb, const ushort* __restrict__ WF2,
           float* __restrict__ ST) {
    const int t = threadIdx.x;
    const int lane = t & 63;
    const int w = t >> 6;
    const int row0 = blockIdx.x * 256 + w * 64;

    int r0 = row0 + (lane & 31);
    int r1 = r0 + 32;
    if (r0 > NN - 1) r0 = NN - 1;
    if (r1 > NN - 1) r1 = NN - 1;
    const ushort* a0p = Hb + (size_t)r0 * HID + (lane >> 5) * 8;
    const ushort* a1p = Hb + (size_t)r1 * HID + (lane >> 5) * 8;

    f32x16 acc0 = {0,0,0,0,0,0,0,0,0,0,0,0,0,0,0,0};
    f32x16 acc1 = acc0;

    #pragma unroll
    for (int kk = 0; kk < 8; ++kk) {
        const s16x8 a0 = *(const s16x8*)(a0p + kk * 16);
        const s16x8 a1 = *(const s16x8*)(a1p + kk * 16);
        const s16x8 b  = *(const s16x8*)(WF2 + (size_t)(kk * 64 + lane) * 8);
        acc0 = __builtin_amdgcn_mfma_f32_32x32x16_bf16(a0, b, acc0, 0, 0, 0);
        acc1 = __builtin_amdgcn_mfma_f32_32x32x16_bf16(a1, b, acc1, 0, 0, 0);
    }

    const int col = lane & 31;
    const int crow4 = 4 * (lane >> 5);
    #pragma unroll
    for (int g = 0; g < 16; ++g) {
        const int row = row0 + (g & 3) + 8 * (g >> 2) + crow4;
        if (row < NN)      ST[(size_t)row * 32 + col] = acc0[g];
        if (row + 32 < NN) ST[(size_t)(row + 32) * 32 + col] = acc1[g];
    }
}

// ---------------------------------------------------------------------------
// Final: out[b][j] = S[node_b][j] + (1/16)*sum_d T[nbr(node_b,d)][j]
// ---------------------------------------------------------------------------
__global__ __launch_bounds__(256)
void final_out(const int* __restrict__ nodes, const int* __restrict__ nidx,
               const float* __restrict__ ST, float* __restrict__ out) {
    const int g = blockIdx.x * 256 + threadIdx.x;
    const int b = g >> 4;
    const int j = g & 15;
    const int node = nodes[b];
    const float s = ST[(size_t)node * 32 + j];
    const int* nb = nidx + (size_t)node * DEG;
    float acc = 0.f;
    #pragma unroll
    for (int d = 0; d < DEG; ++d)
        acc += ST[(size_t)nb[d] * 32 + 16 + j];
    out[g] = fmaf(acc, 1.0f / 16.0f, s);
}

extern "C" void kernel_launch(void* const* d_in, const int* in_sizes, int n_in,
                              void* d_out, int out_size, void* d_ws, size_t ws_size,
                              hipStream_t stream) {
    const int* nodes = (const int*)d_in[0];
    const int* nidx  = (const int*)d_in[1];
    const float* X   = (const float*)d_in[2];
    const float* W1  = (const float*)d_in[3];
    const float* W2  = (const float*)d_in[4];
    float* out = (float*)d_out;

    // ws: Qb bf16 25.6MB | Pb bf16 25.6MB | ST fp32 12.8MB | WFh 64KB | WFl 64KB | WF2 8KB
    ushort* Qb = (ushort*)d_ws;
    ushort* Pb = Qb + (size_t)NN * HID;
    float*  ST = (float*)(Pb + (size_t)NN * HID);
    ushort* WFh = (ushort*)(ST + (size_t)NN * 32);
    ushort* WFl = WFh + 64 * 64 * 8;
    ushort* WF2 = WFl + 64 * 64 * 8;

    wf_prep<<<18, 256, 0, stream>>>(W1, W2, WFh, WFl, WF2);
    gemm1<<<782, 256, 0, stream>>>(X, WFh, WFl, Qb, Pb);
    aggregate<<<(NN * 16) / 256, 256, 0, stream>>>(nidx, Pb, Qb);
    gemm2<<<391, 256, 0, stream>>>(Qb, WF2, ST);
    final_out<<<(NB * NC) / 256, 256, 0, stream>>>(nodes, nidx, ST, out);
}

// Round 4
// 102.024 us; speedup vs baseline: 2.8003x; 1.1784x over previous
//
#include <hip/hip_runtime.h>
#include <hip/hip_bf16.h>

#define NN 100000
#define DEG 16
#define NF 128
#define HID 128
#define NC 16
#define NB 10000

typedef float f32x16 __attribute__((ext_vector_type(16)));
typedef short s16x8 __attribute__((ext_vector_type(8)));

__device__ __forceinline__ ushort f2bf(float f) {   // round-to-nearest-even
    unsigned u = __builtin_bit_cast(unsigned, f);
    return (ushort)((u + 0x7FFFu + ((u >> 16) & 1u)) >> 16);
}
__device__ __forceinline__ float bf2f(ushort h) {
    return __builtin_bit_cast(float, (unsigned)h << 16);
}
// pack 8 fp32 -> 8 bf16 (RNE)
__device__ __forceinline__ s16x8 pack8(float4 a, float4 b) {
    float v[8] = {a.x, a.y, a.z, a.w, b.x, b.y, b.z, b.w};
    ushort o[8];
    #pragma unroll
    for (int j = 0; j < 8; ++j) o[j] = f2bf(v[j]);
    return *(const s16x8*)o;
}
// XOR swizzle within a 256B LDS row: 16 slots of 16B (T2, conflict-free b128)
__device__ __forceinline__ int swz16(int row, int bo) {
    return row * 256 + (bo ^ ((row & 15) << 4));
}

// ---------------------------------------------------------------------------
// Prep: W1 -> bf16 MFMA B-fragments WFh; W2 -> WF2.
// WFh frag (c,kk): lane l holds Wb[c*32+(l&31)][kk*16+(l>>5)*8 .. +8]
//   Wb[j][k] = j<128 ? W1[j][k] : W1[j-128][128+k]
// WF2 frag (kk):   lane l holds W2b[(l&31)][kk*16+(l>>5)*8 .. +8]
//   W2b[j][k] = j<16 ? W2[j][k] : W2[j-16][128+k]
// ---------------------------------------------------------------------------
__global__ __launch_bounds__(256)
void wf_prep(const float* __restrict__ W1, const float* __restrict__ W2,
             ushort* __restrict__ WFh, ushort* __restrict__ WF2) {
    const int t = blockIdx.x * 256 + threadIdx.x;
    if (t >= 72 * 64) return;
    const int frag = t >> 6;
    const int lane = t & 63;
    const int k0 = (frag & 7) * 16 + (lane >> 5) * 8;

    if (frag < 64) {
        const int vcol = (frag >> 3) * 32 + (lane & 31);
        const float* src = (vcol < 128) ? W1 + (size_t)vcol * 256
                                        : W1 + (size_t)(vcol - 128) * 256 + 128;
        ushort hh[8];
        #pragma unroll
        for (int j = 0; j < 8; ++j) hh[j] = f2bf(src[k0 + j]);
        *(uint4*)(WFh + (size_t)t * 8) = *(const uint4*)hh;
    } else {
        const int vcol = lane & 31;
        const float* src = (vcol < 16) ? W2 + (size_t)vcol * 256
                                       : W2 + (size_t)(vcol - 16) * 256 + 128;
        ushort hh[8];
        #pragma unroll
        for (int j = 0; j < 8; ++j) hh[j] = f2bf(src[k0 + j]);
        *(uint4*)(WF2 + (size_t)((frag - 64) * 64 + lane) * 8) = *(const uint4*)hh;
    }
}

// ---------------------------------------------------------------------------
// GEMM1 (single-pass bf16, no LDS): block = 128 rows x 256 cols, K=128.
// A from global fp32 (RNE-packed to bf16 in regs), B from WFh (L2-hot).
// Out: cols<128 -> Qb, else Pb (both bf16).
// ---------------------------------------------------------------------------
__global__ __launch_bounds__(256, 2)
void gemm1(const float* __restrict__ X, const ushort* __restrict__ WFh,
           ushort* __restrict__ Qb, ushort* __restrict__ Pb) {
    const int t = threadIdx.x;
    const int lane = t & 63;
    const int w = t >> 6;
    const int wm = w >> 1, wn = w & 1;
    const int row0 = blockIdx.x * 128;

    int r0 = row0 + wm * 64 + (lane & 31);
    int r1 = r0 + 32;
    if (r0 > NN - 1) r0 = NN - 1;
    if (r1 > NN - 1) r1 = NN - 1;
    const float* a0p = X + (size_t)r0 * NF + (lane >> 5) * 8;
    const float* a1p = X + (size_t)r1 * NF + (lane >> 5) * 8;

    f32x16 acc[2][4];
    #pragma unroll
    for (int m = 0; m < 2; ++m)
        #pragma unroll
        for (int n = 0; n < 4; ++n)
            acc[m][n] = (f32x16){0,0,0,0,0,0,0,0,0,0,0,0,0,0,0,0};

    #pragma unroll
    for (int kk = 0; kk < 8; ++kk) {
        const s16x8 a0h = pack8(*(const float4*)(a0p + kk * 16),
                                *(const float4*)(a0p + kk * 16 + 4));
        const s16x8 a1h = pack8(*(const float4*)(a1p + kk * 16),
                                *(const float4*)(a1p + kk * 16 + 4));
        #pragma unroll
        for (int n = 0; n < 4; ++n) {
            const size_t fo = (size_t)(((wn * 4 + n) * 8 + kk) * 64 + lane) * 8;
            const s16x8 bh = *(const s16x8*)(WFh + fo);
            acc[0][n] = __builtin_amdgcn_mfma_f32_32x32x16_bf16(a0h, bh, acc[0][n], 0, 0, 0);
            acc[1][n] = __builtin_amdgcn_mfma_f32_32x32x16_bf16(a1h, bh, acc[1][n], 0, 0, 0);
        }
    }

    // C/D layout: col=lane&31, row=(g&3)+8*(g>>2)+4*(lane>>5)
    const int ccol = lane & 31;
    const int crow4 = 4 * (lane >> 5);
    #pragma unroll
    for (int m = 0; m < 2; ++m) {
        #pragma unroll
        for (int n = 0; n < 4; ++n) {
            const int col = wn * 128 + n * 32 + ccol;
            ushort* base = (col < 128) ? (Qb + col) : (Pb + col - 128);
            #pragma unroll
            for (int g = 0; g < 16; ++g) {
                const int row = row0 + wm * 64 + m * 32 + (g & 3) + 8 * (g >> 2) + crow4;
                if (row < NN) base[(size_t)row * HID] = f2bf(acc[m][n][g]);
            }
        }
    }
}

// ---------------------------------------------------------------------------
// Fused aggregate + GEMM2. Block = 256 nodes.
// Phase A: h1[n] = relu(Qb[n] + mean_d Pb[nbr(n,d)]) -> swizzled LDS (bf16).
// Phase B: ST = h1 @ W2frag (MFMA from LDS) -> STb (bf16).
// h1 never touches HBM.
// ---------------------------------------------------------------------------
__global__ __launch_bounds__(256, 2)
void agg_gemm2(const int* __restrict__ nidx, const ushort* __restrict__ Pb,
               const ushort* __restrict__ Qb, const ushort* __restrict__ WF2,
               ushort* __restrict__ STb) {
    __shared__ char hs[256 * 256];  // 64KB: 256 rows x 128 bf16, swizzled
    const int t = threadIdx.x;
    const int node0 = blockIdx.x * 256;
    const int sl = t & 15;   // slice lane (16B of a row)
    const int ng = t >> 4;   // node group 0..15

    const float inv = 1.0f / 16.0f;
    #pragma unroll 1
    for (int it = 0; it < 16; ++it) {
        const int r = ng + it * 16;          // local row
        int node = node0 + r;
        if (node > NN - 1) node = NN - 1;
        const int myn = nidx[(size_t)node * DEG + sl];
        uint off[16];
        #pragma unroll
        for (int d = 0; d < 16; ++d)
            off[d] = (uint)__shfl(myn, d, 16) * 256u + (uint)sl * 16u;
        float s[8] = {0, 0, 0, 0, 0, 0, 0, 0};
        #pragma unroll
        for (int d = 0; d < 16; ++d) {
            const s16x8 v = *(const s16x8*)((const char*)Pb + off[d]);
            #pragma unroll
            for (int j = 0; j < 8; ++j) s[j] += bf2f((ushort)v[j]);
        }
        const s16x8 q = *(const s16x8*)(Qb + (size_t)node * HID + sl * 8);
        ushort o[8];
        #pragma unroll
        for (int j = 0; j < 8; ++j)
            o[j] = f2bf(fmaxf(fmaf(s[j], inv, bf2f((ushort)q[j])), 0.f));
        *(uint4*)(hs + swz16(r, sl * 16)) = *(const uint4*)o;
    }
    __syncthreads();

    // Phase B: 4 waves; wave w -> local rows w*64 .. w*64+63 (2x32 frags)
    const int lane = t & 63;
    const int w = t >> 6;
    const int rl = w * 64;

    f32x16 acc0 = {0,0,0,0,0,0,0,0,0,0,0,0,0,0,0,0};
    f32x16 acc1 = acc0;
    #pragma unroll
    for (int kk = 0; kk < 8; ++kk) {
        const int kb = kk * 32 + (lane >> 5) * 16;
        const s16x8 a0 = *(const s16x8*)(hs + swz16(rl + (lane & 31), kb));
        const s16x8 a1 = *(const s16x8*)(hs + swz16(rl + 32 + (lane & 31), kb));
        const s16x8 b  = *(const s16x8*)(WF2 + (size_t)(kk * 64 + lane) * 8);
        acc0 = __builtin_amdgcn_mfma_f32_32x32x16_bf16(a0, b, acc0, 0, 0, 0);
        acc1 = __builtin_amdgcn_mfma_f32_32x32x16_bf16(a1, b, acc1, 0, 0, 0);
    }

    const int col = lane & 31;
    const int crow4 = 4 * (lane >> 5);
    #pragma unroll
    for (int g = 0; g < 16; ++g) {
        const int row = node0 + rl + (g & 3) + 8 * (g >> 2) + crow4;
        if (row < NN)      STb[(size_t)row * 32 + col] = f2bf(acc0[g]);
        if (row + 32 < NN) STb[(size_t)(row + 32) * 32 + col] = f2bf(acc1[g]);
    }
}

// ---------------------------------------------------------------------------
// Final: out[b][j] = S[node_b][j] + (1/16)*sum_d T[nbr(node_b,d)][j]
// ---------------------------------------------------------------------------
__global__ __launch_bounds__(256)
void final_out(const int* __restrict__ nodes, const int* __restrict__ nidx,
               const ushort* __restrict__ STb, float* __restrict__ out) {
    const int g = blockIdx.x * 256 + threadIdx.x;
    const int b = g >> 4;
    const int j = g & 15;
    const int node = nodes[b];
    const float s = bf2f(STb[(size_t)node * 32 + j]);
    const int* nb = nidx + (size_t)node * DEG;
    float acc = 0.f;
    #pragma unroll
    for (int d = 0; d < DEG; ++d)
        acc += bf2f(STb[(size_t)nb[d] * 32 + 16 + j]);
    out[g] = fmaf(acc, 1.0f / 16.0f, s);
}

extern "C" void kernel_launch(void* const* d_in, const int* in_sizes, int n_in,
                              void* d_out, int out_size, void* d_ws, size_t ws_size,
                              hipStream_t stream) {
    const int* nodes = (const int*)d_in[0];
    const int* nidx  = (const int*)d_in[1];
    const float* X   = (const float*)d_in[2];
    const float* W1  = (const float*)d_in[3];
    const float* W2  = (const float*)d_in[4];
    float* out = (float*)d_out;

    // ws: Qb 25.6MB | Pb 25.6MB | STb 6.4MB | WFh 64KB | WF2 8KB
    ushort* Qb  = (ushort*)d_ws;
    ushort* Pb  = Qb + (size_t)NN * HID;
    ushort* STb = Pb + (size_t)NN * HID;
    ushort* WFh = STb + (size_t)NN * 32;
    ushort* WF2 = WFh + 64 * 64 * 8;

    wf_prep<<<18, 256, 0, stream>>>(W1, W2, WFh, WF2);
    gemm1<<<782, 256, 0, stream>>>(X, WFh, Qb, Pb);
    agg_gemm2<<<391, 256, 0, stream>>>(nidx, Pb, Qb, WF2, STb);
    final_out<<<(NB * NC) / 256, 256, 0, stream>>>(nodes, nidx, STb, out);
}